// Round 2
// baseline (526.165 us; speedup 1.0000x reference)
//
#include <hip/hip_runtime.h>
#include <math.h>

// Pipeline (float-input dtype auto-detected bf16 vs fp32; internal fp64/fp32/bf16):
//  0. detect     : 1 wave inspects pentachora u16 exponent fields -> flag (1=bf16 inputs, 0=fp32)
//  0b prep_x     : x -> bf16 xb[4096][512]
//  0c transpose_w: Wqkv->Wt1[1536][512] bf16 and Wout->Wt2[512][512] bf16, one combined launch
//  1. penta_sums : TOKEN-SPARSE — only the <=2048 vocab rows named by token_ids are consumed
//  2. coords     : fp64 unrolled no-pivot Cayley-Menger det + stats + cantor -> ctok[i]
//  3. groups     : counting-sort queries by coord -> perm[2048]; repq[q] = lowest-index query
//                  with the same coord (identical routes). Enables route dedup + L2 locality.
//  4. routes     : top-64 by integer coord distance — computed ONLY for representative queries
//  5. gemm qkv   : LDS-free direct-global bf16 MFMA (A[M,K] row frag, Wt[N,K] row frag)
//  6. attn       : queries processed in coord-sorted order with XCD-contiguous block swizzle:
//                  each XCD's gather working set (~1.6 MB) fits its private L2. Routes read
//                  via repq (shared across same-coord queries).
//  7. gemm out   : same direct GEMM -> d_out (dtype per flag)

typedef unsigned short u16;
typedef short short8 __attribute__((ext_vector_type(8)));
typedef u16 u16x8 __attribute__((ext_vector_type(8)));
typedef float floatx4 __attribute__((ext_vector_type(4)));

#define NVOCAB 32000
#define NSEQ 2048

__device__ inline float b2f(u16 u){
  union{unsigned int i; float f;} x; x.i = ((unsigned int)u)<<16; return x.f;
}
__device__ inline u16 f2b(float f){
  union{float f; unsigned int u;} x; x.f = f;
  unsigned int u = x.u;
  u += 0x7fffu + ((u >> 16) & 1u);   // RNE
  return (u16)(u >> 16);
}
__device__ inline double shfl_xor_d(double v, int m){
  union{double d; int i[2];} x; x.d = v;
  x.i[0] = __shfl_xor(x.i[0], m, 64);
  x.i[1] = __shfl_xor(x.i[1], m, 64);
  return x.d;
}

// ---------------- Stage 0: input dtype detection ----------------
__global__ void detect_kernel(const u16* __restrict__ p, int* __restrict__ flag){
  int lane = threadIdx.x;
  u16 u = p[lane*2];
  int e = (u >> 7) & 0xff;
  bool pass = (e >= 96 && e <= 144);
  unsigned long long m = __ballot(pass);
  if (lane == 0) *flag = (m == ~0ull) ? 1 : 0;
}

// ---------------- Stage 0b: x -> bf16 (8 elements/thread) ----------------
__global__ __launch_bounds__(256) void prep_x_kernel(const void* __restrict__ x,
                                                     const int* __restrict__ flagp,
                                                     u16* __restrict__ xb){
  int f = *flagp;
  size_t i = ((size_t)blockIdx.x*256 + threadIdx.x)*8;
  if (f){
    *(u16x8*)(xb+i) = *(const u16x8*)((const u16*)x + i);
  } else {
    const float* xf = (const float*)x + i;
    float4 a = *(const float4*)xf;
    float4 b = *(const float4*)(xf+4);
    u16x8 o;
    o[0]=f2b(a.x); o[1]=f2b(a.y); o[2]=f2b(a.z); o[3]=f2b(a.w);
    o[4]=f2b(b.x); o[5]=f2b(b.y); o[6]=f2b(b.z); o[7]=f2b(b.w);
    *(u16x8*)(xb+i) = o;
  }
}

// ---------------- Stage 0c: combined W[K][N] -> Wt[N][K] bf16 (K=512) ----------------
__global__ __launch_bounds__(256) void transpose_w_kernel(const void* __restrict__ W1,
                                                          const void* __restrict__ W2,
                                                          u16* __restrict__ Wt1,
                                                          u16* __restrict__ Wt2,
                                                          const int* __restrict__ flagp){
  int f = *flagp;
  __shared__ u16 tile[32][33];
  const int K = 512;
  int bx = blockIdx.x, k0 = blockIdx.y*32;
  const void* W; u16* Wt; int N, n0;
  if (bx < 48){ W = W1; Wt = Wt1; N = 1536; n0 = bx*32; }
  else        { W = W2; Wt = Wt2; N = 512;  n0 = (bx-48)*32; }
  int tx = threadIdx.x & 31, ty = threadIdx.x >> 5;
  #pragma unroll
  for (int i=0;i<32;i+=8){
    int k = k0+ty+i, n = n0+tx;
    u16 v = f ? ((const u16*)W)[(size_t)k*N + n]
              : f2b(((const float*)W)[(size_t)k*N + n]);
    tile[ty+i][tx] = v;
  }
  __syncthreads();
  #pragma unroll
  for (int i=0;i<32;i+=8){
    Wt[(size_t)(n0+ty+i)*K + k0+tx] = tile[tx][ty+i];
  }
}

// ---------------- Stage 1: per-TOKEN pair/centroid sums (fp64), wave per token slot ----------------
__global__ __launch_bounds__(256) void penta_sums_kernel(const void* __restrict__ penta,
                                                         const int* __restrict__ flagp,
                                                         const int* __restrict__ tok,
                                                         double* __restrict__ sums){
  int f = *flagp;
  int slot = blockIdx.x*4 + (threadIdx.x>>6);   // token slot, 4 waves/block
  int w = tok[slot];                            // vocab row for this token
  int lane = threadIdx.x & 63;
  float pf[5][8];
  if (f){   // bf16 inputs
    const u16* base = (const u16*)penta + (size_t)w*2560 + lane*8;
    #pragma unroll
    for (int i=0;i<5;i++){
      u16x8 u = *(const u16x8*)(base + i*512);
      #pragma unroll
      for (int j=0;j<8;j++) pf[i][j] = b2f(u[j]);
    }
  } else {  // fp32 inputs
    const float* base = (const float*)penta + (size_t)w*2560 + lane*8;
    #pragma unroll
    for (int i=0;i<5;i++){
      float4 f0 = *(const float4*)(base + i*512);
      float4 f1 = *(const float4*)(base + i*512 + 4);
      pf[i][0]=f0.x; pf[i][1]=f0.y; pf[i][2]=f0.z; pf[i][3]=f0.w;
      pf[i][4]=f1.x; pf[i][5]=f1.y; pf[i][6]=f1.z; pf[i][7]=f1.w;
    }
  }
  double acc[15];
  #pragma unroll
  for (int k=0;k<15;k++) acc[k]=0.0;
  #pragma unroll
  for (int j=0;j<8;j++){
    double p[5];
    #pragma unroll
    for (int i=0;i<5;i++) p[i] = (double)pf[i][j];
    double mean = (p[0]+p[1]+p[2]+p[3]+p[4])*0.2;
    int idx=0;
    #pragma unroll
    for (int a=0;a<5;a++)
      #pragma unroll
      for (int b=a+1;b<5;b++){ double d=p[a]-p[b]; acc[idx++] += d*d; }
    #pragma unroll
    for (int i=0;i<5;i++){ double d=p[i]-mean; acc[10+i] += d*d; }
  }
  #pragma unroll
  for (int k=0;k<15;k++){
    double s = acc[k];
    for (int off=32; off; off>>=1) s += shfl_xor_d(s, off);
    acc[k]=s;
  }
  if (lane==0){
    double* o = sums + (size_t)slot*15;
    #pragma unroll
    for (int k=0;k<15;k++) o[k]=acc[k];
  }
}

// ---------------- Stage 2: fp64 unrolled det + stats + cantor, one thread per token slot ----------------
__global__ __launch_bounds__(256) void coords_kernel(const double* __restrict__ sums,
                                                     int* __restrict__ ctok){
  int v = blockIdx.x*256 + threadIdx.x;
  if (v >= NSEQ) return;
  const double* s = sums + (size_t)v*15;
  double ds[10], cd2[5];
  #pragma unroll
  for (int k=0;k<10;k++) ds[k]=s[k];
  #pragma unroll
  for (int k=0;k<5;k++) cd2[k]=s[10+k];
  // Cayley-Menger with rows 0,1 pre-swapped: S[0]=[1,0,d01..], S[1]=[0,1,1,1,1,1].
  // det(M_orig) = -det(S); volume^2 = -det(M)/9216 = det(S)/9216.
  // No pivoting needed: pivot0=1, pivot1=1, later pivots ~ -1024 (dist_sq ~ 2*512).
  double M[6][6];
  M[0][0]=1.0; M[0][1]=0.0; M[0][2]=ds[0]; M[0][3]=ds[1]; M[0][4]=ds[2]; M[0][5]=ds[3];
  M[1][0]=0.0; M[1][1]=1.0; M[1][2]=1.0;   M[1][3]=1.0;   M[1][4]=1.0;   M[1][5]=1.0;
  M[2][0]=1.0; M[2][1]=ds[0]; M[2][2]=0.0;   M[2][3]=ds[4]; M[2][4]=ds[5]; M[2][5]=ds[6];
  M[3][0]=1.0; M[3][1]=ds[1]; M[3][2]=ds[4]; M[3][3]=0.0;   M[3][4]=ds[7]; M[3][5]=ds[8];
  M[4][0]=1.0; M[4][1]=ds[2]; M[4][2]=ds[5]; M[4][3]=ds[7]; M[4][4]=0.0;   M[4][5]=ds[9];
  M[5][0]=1.0; M[5][1]=ds[3]; M[5][2]=ds[6]; M[5][3]=ds[8]; M[5][4]=ds[9]; M[5][5]=0.0;
  double det=1.0;
  #pragma unroll
  for (int c=0;c<6;c++){
    double pv = M[c][c];
    det *= pv;
    double inv = 1.0/pv;
    #pragma unroll
    for (int r=c+1;r<6;r++){
      double fq = M[r][c]*inv;
      #pragma unroll
      for (int cc=c+1;cc<6;cc++) M[r][cc] -= fq*M[c][cc];
    }
  }
  double volume = sqrt(fmax(det/9216.0, 0.0));
  double vn = 1.0/(1.0+exp(-10.0*volume));
  double me=0.0, e[10];
  #pragma unroll
  for (int k=0;k<10;k++){ e[k]=sqrt(ds[k]); me+=e[k]; }
  me *= 0.1;
  double var=0.0;
  #pragma unroll
  for (int k=0;k<10;k++){ double d=e[k]-me; var+=d*d; }
  double se = sqrt(var/9.0);                    // ddof=1
  double er = 1.0/(1.0+exp(-(se/(me+1e-6))));
  double mc=0.0, cd[5];
  #pragma unroll
  for (int k=0;k<5;k++){ cd[k]=sqrt(cd2[k]); mc+=cd[k]; }
  mc *= 0.2;
  double v2=0.0;
  #pragma unroll
  for (int k=0;k<5;k++){ double d=cd[k]-mc; v2+=d*d; }
  double sp = sqrt(v2/4.0);                     // ddof=1
  double sn = 1.0/(1.0+exp(-sp));
  const double EPSd = 1e-6;
  double x = 0.4*vn + 0.3*er + 0.3*sn;
  x = fmin(fmax(x, EPSd), 1.0-EPSd);
  double bump = (vn+er+sn)*0.01;
  double cv=0.0, factor=0.5;
  #pragma unroll
  for (int it=0; it<8; it++){
    double xs = x*3.0;
    double frac = xs - floor(xs);
    if (xs >= 2.0) cv += factor;
    x = fmin(fmax(frac + bump, EPSd), 1.0-EPSd);
    factor *= 0.5;
  }
  cv = fmin(fmax(cv,0.0),1.0);
  ctok[v] = (int)(cv*256.0 + 0.5);              // exact multiple of 1/256 -> exact int (max 255)
}

// ---------------- Stage 3: coord grouping — perm (counting sort) + representatives ----------------
__global__ __launch_bounds__(256) void groups_kernel(const int* __restrict__ ctok,
                                                     int* __restrict__ perm,
                                                     int* __restrict__ repq){
  __shared__ int hist[257];
  __shared__ int repc[257];
  __shared__ int offs[257];
  int tid = threadIdx.x;
  for (int i=tid;i<257;i+=256){ hist[i]=0; repc[i]=0x7fffffff; }
  __syncthreads();
  for (int j=tid;j<NSEQ;j+=256){
    int c = ctok[j];
    atomicAdd(&hist[c],1);
    atomicMin(&repc[c], j);
  }
  __syncthreads();
  if (tid==0){
    int acc=0;
    for (int i=0;i<257;i++){ offs[i]=acc; acc+=hist[i]; }
  }
  __syncthreads();
  for (int j=tid;j<NSEQ;j+=256){
    int c = ctok[j];
    int pos = atomicAdd(&offs[c],1);
    perm[pos]=j;               // order within a group is irrelevant (locality only)
    repq[j]=repc[c];           // lowest-index query with identical coord -> identical routes
  }
}

// ---------------- Stage 4: top-64 neighbors — only for representative queries ----------------
__global__ __launch_bounds__(256) void routes_kernel(const int* __restrict__ ctok,
                                                     const int* __restrict__ repq,
                                                     int* __restrict__ routes){
  int q = blockIdx.x;
  if (repq[q] != q) return;    // same coord -> identical routes; computed once per group
  __shared__ int cs[NSEQ];
  __shared__ int hist[256];
  __shared__ int scn[256];
  __shared__ int cnts[256];
  __shared__ int params[3];   // T, need, out-counter
  int tid = threadIdx.x;
  for (int j=tid; j<NSEQ; j+=256) cs[j] = ctok[j];
  hist[tid] = 0;
  if (tid==0) params[2]=0;
  __syncthreads();
  int cq = cs[q];
  int base = tid*8;
  int dloc[8];
  #pragma unroll
  for (int i=0;i<8;i++){
    int d = cs[base+i] - cq; d = d<0 ? -d : d;
    dloc[i] = d;
    atomicAdd(&hist[d], 1);
  }
  __syncthreads();
  // parallel inclusive scan of hist -> scn
  scn[tid] = hist[tid];
  __syncthreads();
  #pragma unroll
  for (int off=1; off<256; off<<=1){
    int cur = scn[tid];
    int add = (tid>=off) ? scn[tid-off] : 0;
    __syncthreads();
    scn[tid] = cur + add;
    __syncthreads();
  }
  {
    int incl = scn[tid];
    int prev = (tid==0) ? 0 : scn[tid-1];
    if (incl >= 64 && prev < 64){ params[0]=tid; params[1]=64-prev; }
  }
  __syncthreads();
  int T=params[0], need=params[1];
  int ceq=0;
  #pragma unroll
  for (int i=0;i<8;i++) ceq += (dloc[i]==T) ? 1 : 0;
  // parallel scan of per-thread equal-counts -> exclusive rank base
  cnts[tid]=ceq;
  __syncthreads();
  #pragma unroll
  for (int off=1; off<256; off<<=1){
    int cur = cnts[tid];
    int add = (tid>=off) ? cnts[tid-off] : 0;
    __syncthreads();
    cnts[tid] = cur + add;
    __syncthreads();
  }
  int rank = cnts[tid] - ceq;
  int* rq = routes + q*64;
  #pragma unroll
  for (int i=0;i<8;i++){
    int d = dloc[i];
    bool sel = false;
    if (d < T) sel = true;
    else if (d == T){ sel = (rank < need); rank++; }
    if (sel){
      int pos = atomicAdd(&params[2], 1);
      rq[pos] = base + i;   // set semantics: order within the 64 doesn't matter for softmax
    }
  }
}

// ---------------- Stages 5/7: LDS-free direct-global bf16 MFMA GEMM ----------------
template<int C_FOLLOW>
__global__ __launch_bounds__(256) void gemm_direct(const u16* __restrict__ A,
    const u16* __restrict__ Wt, const void* __restrict__ bias, void* __restrict__ Cout,
    const int* __restrict__ flagp, int M, int N, int K)
{
  int f = *flagp;
  bool c_bf16 = C_FOLLOW ? (f==1) : true;
  int tid = threadIdx.x;
  int wv = tid>>6, lane = tid&63, lr = lane&15, lq = lane>>4;
  int m0 = blockIdx.y<<6, n0 = blockIdx.x<<6;
  const u16* Arow = A  + (size_t)(m0 + (wv<<4) + lr)*K + (lq<<3);
  const u16* Wr0  = Wt + (size_t)(n0 + lr)*K + (lq<<3);
  size_t wstep = (size_t)16*K;
  floatx4 acc[4];
  #pragma unroll
  for (int t=0;t<4;t++) acc[t] = (floatx4){0.f,0.f,0.f,0.f};
  #pragma unroll 4
  for (int k0=0;k0<K;k0+=32){
    short8 af = *(const short8*)(Arow + k0);
    #pragma unroll
    for (int t4=0;t4<4;t4++){
      short8 bfv = *(const short8*)(Wr0 + (size_t)t4*wstep + k0);
      acc[t4] = __builtin_amdgcn_mfma_f32_16x16x32_bf16(af, bfv, acc[t4], 0, 0, 0);
    }
  }
  // C/D: row = lq*4 + r, col = lane&15
  #pragma unroll
  for (int t4=0;t4<4;t4++){
    #pragma unroll
    for (int r=0;r<4;r++){
      int m = m0 + (wv<<4) + (lq<<2) + r;
      int n = n0 + (t4<<4) + lr;
      float bv = f ? b2f(((const u16*)bias)[n]) : ((const float*)bias)[n];
      float val = acc[t4][r] + bv;
      if (c_bf16) ((u16*)Cout)[(size_t)m*N + n] = f2b(val);
      else        ((float*)Cout)[(size_t)m*N + n] = val;
    }
  }
}

// ---------------- Stage 6: gather attention, coord-sorted order, 4 waves/block ----------------
// wave -> (slot, batch): slot = coord-sorted query rank. XCD-contiguous block swizzle keeps
// each XCD's gather working set (~1/8 of qkv rows, grouped by coord) inside its private L2.
//  k-phase: for each neighbor j, lane covers q/k dims [lane*8,lane*8+8); partial dot
//           reduced over the 8-lane head group via shfl_xor(1,2,4); score -> LDS.
//  softmax: lane=(h,jg) handles 8 scores of head h; group-reduce max/sum; probs -> LDS.
//  v-phase: lane=(h,dg) accumulates 8 output dims over j with coalesced v-row loads.
__global__ __launch_bounds__(256) void attn_kernel(const u16* __restrict__ qkv,
                                                   const int* __restrict__ routes,
                                                   const int* __restrict__ perm,
                                                   const int* __restrict__ repq,
                                                   u16* __restrict__ outa){
  __shared__ float sc[4][8*65];   // (65h+j)%32=(h+j)%32 -> conflict-free across heads
  __shared__ int rbuf[4][64];
  int tid = threadIdx.x;
  int wv = tid>>6, lane = tid&63;
  int bid = blockIdx.x;
  int swz = ((bid&7)<<7) + (bid>>3);   // 1024 blocks, 1024%8==0 -> bijective XCD-contiguous
  int idx = swz*4 + wv;                // 0..4095
  int slot = idx>>1;                   // coord-sorted rank 0..2047
  int b = idx&1;                       // batch
  int q = perm[slot];
  rbuf[wv][lane] = routes[(repq[q]<<6) + lane];
  int h8 = lane>>3;               // head this lane's dims belong to
  const u16* kb = qkv + (size_t)(b<<11)*1536;
  // my 8 q dims (coalesced 1KB load across the wave)
  float qv[8];
  {
    u16x8 qraw = *(const u16x8*)(kb + (size_t)q*1536 + lane*8);
    #pragma unroll
    for (int t=0;t<8;t++) qv[t] = b2f(qraw[t]);
  }
  __syncthreads();
  // k-phase
  for (int j=0;j<64;j++){
    int rj = rbuf[wv][j];
    u16x8 kraw = *(const u16x8*)(kb + (size_t)rj*1536 + 512 + lane*8);
    float p = 0.f;
    #pragma unroll
    for (int t=0;t<8;t++) p = fmaf(b2f(kraw[t]), qv[t], p);
    p += __shfl_xor(p, 1, 64);
    p += __shfl_xor(p, 2, 64);
    p += __shfl_xor(p, 4, 64);
    if ((lane&7)==0) sc[wv][h8*65 + j] = p * 0.125f;   // 1/sqrt(64)
  }
  __syncthreads();
  // softmax per head (8-lane group owns a head; each lane 8 scores)
  {
    int jg = (lane&7)<<3;
    float sv[8];
    float m = -1e30f;
    #pragma unroll
    for (int t=0;t<8;t++){ sv[t] = sc[wv][h8*65 + jg + t]; m = fmaxf(m, sv[t]); }
    m = fmaxf(m, __shfl_xor(m, 1, 64));
    m = fmaxf(m, __shfl_xor(m, 2, 64));
    m = fmaxf(m, __shfl_xor(m, 4, 64));
    float s = 0.f;
    #pragma unroll
    for (int t=0;t<8;t++){ sv[t] = expf(sv[t]-m); s += sv[t]; }
    s += __shfl_xor(s, 1, 64);
    s += __shfl_xor(s, 2, 64);
    s += __shfl_xor(s, 4, 64);
    float inv = 1.f/s;
    #pragma unroll
    for (int t=0;t<8;t++) sc[wv][h8*65 + jg + t] = sv[t]*inv;
  }
  __syncthreads();
  // v-phase: lane=(h8, dg) accumulates out dims [h8*64+dg, +8)
  int dg = (lane&7)<<3;
  const u16* vb = kb + 1024 + (h8<<6) + dg;
  float acc8[8];
  #pragma unroll
  for (int t=0;t<8;t++) acc8[t]=0.f;
  for (int j=0;j<64;j++){
    float p = sc[wv][h8*65 + j];
    u16x8 v8 = *(const u16x8*)(vb + (size_t)rbuf[wv][j]*1536);
    #pragma unroll
    for (int t=0;t<8;t++) acc8[t] = fmaf(p, b2f(v8[t]), acc8[t]);
  }
  u16x8 o;
  #pragma unroll
  for (int t=0;t<8;t++) o[t] = f2b(acc8[t]);
  *(u16x8*)(outa + (size_t)((b<<11)+q)*512 + (h8<<6) + dg) = o;
}

extern "C" void kernel_launch(void* const* d_in, const int* in_sizes, int n_in,
                              void* d_out, int out_size, void* d_ws, size_t ws_size,
                              hipStream_t stream) {
  const void* penta = d_in[0];   // [32000,5,512]
  const void* x     = d_in[1];   // [2,2048,512]
  const int*  tok   = (const int*)d_in[2];   // [2048]
  const void* Wqkv  = d_in[3];   // [512,1536]
  const void* bqkv  = d_in[4];   // [1536]
  const void* Wout  = d_in[5];   // [512,512]
  const void* bout  = d_in[6];   // [512]

  char* ws = (char*)d_ws;
  int*    flag   = (int*)   (ws + 128000);     // 4 B
  int*    ctok   = (int*)   (ws + 131072);     // 8192 B
  int*    routes = (int*)   (ws + 139264);     // 524288 B   (end 663552)
  double* sums   = (double*)(ws + 663552);     // 245760 B used (token-sparse, end 909312)
  int*    perm   = (int*)   (ws + 917504);     // 8192 B (end 925696)
  int*    repq   = (int*)   (ws + 925696);     // 8192 B (end 933888)
  u16*    xb     = (u16*)   (ws + 4503552);    // 4194304 B  (end 8697856)
  u16*    Wt1    = (u16*)   (ws + 8697856);    // 1572864 B  (end 10270720)
  u16*    Wt2    = (u16*)   (ws + 10270720);   // 524288 B   (end 10795008)
  u16*    qkv    = (u16*)   (ws + 10795008);   // 12582912 B (end 23377920)
  u16*    attn   = (u16*)   (ws + 23377920);   // 4194304 B  (end 27572224 ~ 26.3 MB)

  detect_kernel<<<dim3(1), dim3(64), 0, stream>>>((const u16*)penta, flag);
  prep_x_kernel<<<dim3(1024), dim3(256), 0, stream>>>(x, flag, xb);
  transpose_w_kernel<<<dim3(64,16), dim3(256), 0, stream>>>(Wqkv, Wout, Wt1, Wt2, flag);
  penta_sums_kernel<<<dim3(512), dim3(256), 0, stream>>>(penta, flag, tok, sums);
  coords_kernel<<<dim3(8), dim3(256), 0, stream>>>(sums, ctok);
  groups_kernel<<<dim3(1), dim3(256), 0, stream>>>(ctok, perm, repq);
  routes_kernel<<<dim3(2048), dim3(256), 0, stream>>>(ctok, repq, routes);
  gemm_direct<0><<<dim3(24,64), dim3(256), 0, stream>>>(xb, Wt1, bqkv, (void*)qkv, flag, 4096, 1536, 512);
  attn_kernel<<<dim3(1024), dim3(256), 0, stream>>>(qkv, routes, perm, repq, attn);
  gemm_direct<1><<<dim3(8,64), dim3(256), 0, stream>>>(attn, Wt2, bout, d_out, flag, 4096, 512, 512);
}

// Round 3
// 518.001 us; speedup vs baseline: 1.0158x; 1.0158x over previous
//
#include <hip/hip_runtime.h>
#include <math.h>

// Pipeline (float-input dtype auto-detected bf16 vs fp32; internal fp64/fp32/bf16), 6 launches:
//  1. prep        : fused — x -> bf16 xb[4096][512]  AND  Wqkv/Wout -> Wt1/Wt2 (bf16, transposed).
//                   dtype flag recomputed per-wave from pentachora (128 B ballot, L2 broadcast).
//  2. penta_coords: fused — one wave per TOKEN SLOT: 15 fp64 pair/centroid sums via butterfly
//                   shfl reduce (all lanes hold results), then lane 0 runs the fp64 unrolled
//                   no-pivot Cayley-Menger det + stats + cantor -> ctok[slot]. No sums buffer.
//  3. routes      : per-query block caches ctok in LDS, computes its own representative
//                   (min index with equal coord) -> repq[q]; non-reps exit; reps compute
//                   integer-distance histogram top-64 (parallel scans, tie-break lowest index).
//  4. gemm qkv    : LDS-free direct-global bf16 MFMA (A[M,K] row frag, Wt[N,K] row frag)
//  5. attn        : 4 queries/block (1/wave); coalesced row loads; routes shared via repq.
//  6. gemm out    : same direct GEMM -> d_out (dtype per flag)

typedef unsigned short u16;
typedef short short8 __attribute__((ext_vector_type(8)));
typedef u16 u16x8 __attribute__((ext_vector_type(8)));
typedef float floatx4 __attribute__((ext_vector_type(4)));

#define NVOCAB 32000
#define NSEQ 2048

__device__ inline float b2f(u16 u){
  union{unsigned int i; float f;} x; x.i = ((unsigned int)u)<<16; return x.f;
}
__device__ inline u16 f2b(float f){
  union{float f; unsigned int u;} x; x.f = f;
  unsigned int u = x.u;
  u += 0x7fffu + ((u >> 16) & 1u);   // RNE
  return (u16)(u >> 16);
}
__device__ inline double shfl_xor_d(double v, int m){
  union{double d; int i[2];} x; x.d = v;
  x.i[0] = __shfl_xor(x.i[0], m, 64);
  x.i[1] = __shfl_xor(x.i[1], m, 64);
  return x.d;
}
// Per-wave input dtype detection (identical logic to the old detect_kernel):
// u16 at even indices; bf16 values have exponent in [96,144] for N(0,1) data, fp32 low-halves don't.
__device__ inline int detect_flag(const u16* __restrict__ p){
  int lane = threadIdx.x & 63;
  u16 u = p[lane*2];
  int e = (u >> 7) & 0xff;
  unsigned long long m = __ballot(e >= 96 && e <= 144);
  return (m == ~0ull) ? 1 : 0;
}

// ---------------- Stage 1: fused prep — x->bf16 and W transposes ----------------
__global__ __launch_bounds__(256) void prep_kernel(const void* __restrict__ x,
                                                   const void* __restrict__ W1,
                                                   const void* __restrict__ W2,
                                                   const u16* __restrict__ penta,
                                                   u16* __restrict__ xb,
                                                   u16* __restrict__ Wt1,
                                                   u16* __restrict__ Wt2){
  int f = detect_flag(penta);
  int bid = blockIdx.x;
  if (bid < 1024){
    // x -> bf16, 8 elements/thread
    size_t i = ((size_t)bid*256 + threadIdx.x)*8;
    if (f){
      *(u16x8*)(xb+i) = *(const u16x8*)((const u16*)x + i);
    } else {
      const float* xf = (const float*)x + i;
      float4 a = *(const float4*)xf;
      float4 b = *(const float4*)(xf+4);
      u16x8 o;
      o[0]=f2b(a.x); o[1]=f2b(a.y); o[2]=f2b(a.z); o[3]=f2b(a.w);
      o[4]=f2b(b.x); o[5]=f2b(b.y); o[6]=f2b(b.z); o[7]=f2b(b.w);
      *(u16x8*)(xb+i) = o;
    }
    return;
  }
  // W[K][N] -> Wt[N][K] bf16, K=512. Old grid dim3(64,16) flattened.
  int idx = bid - 1024;          // 0..1023
  int bx = idx & 63;             // 0..63
  int k0 = (idx >> 6) * 32;      // 0..480
  __shared__ u16 tile[32][33];
  const int K = 512;
  const void* W; u16* Wt; int N, n0;
  if (bx < 48){ W = W1; Wt = Wt1; N = 1536; n0 = bx*32; }
  else        { W = W2; Wt = Wt2; N = 512;  n0 = (bx-48)*32; }
  int tx = threadIdx.x & 31, ty = threadIdx.x >> 5;
  #pragma unroll
  for (int i=0;i<32;i+=8){
    int k = k0+ty+i, n = n0+tx;
    u16 v = f ? ((const u16*)W)[(size_t)k*N + n]
              : f2b(((const float*)W)[(size_t)k*N + n]);
    tile[ty+i][tx] = v;
  }
  __syncthreads();
  #pragma unroll
  for (int i=0;i<32;i+=8){
    Wt[(size_t)(n0+ty+i)*K + k0+tx] = tile[tx][ty+i];
  }
}

// ---------------- Stage 2: fused penta sums + coords, one wave per token slot ----------------
__global__ __launch_bounds__(256) void penta_coords_kernel(const void* __restrict__ penta,
                                                           const int* __restrict__ tok,
                                                           int* __restrict__ ctok){
  int f = detect_flag((const u16*)penta);
  int slot = blockIdx.x*4 + (threadIdx.x>>6);   // token slot, 4 waves/block
  int w = tok[slot];                            // vocab row for this token
  int lane = threadIdx.x & 63;
  float pf[5][8];
  if (f){   // bf16 inputs
    const u16* base = (const u16*)penta + (size_t)w*2560 + lane*8;
    #pragma unroll
    for (int i=0;i<5;i++){
      u16x8 u = *(const u16x8*)(base + i*512);
      #pragma unroll
      for (int j=0;j<8;j++) pf[i][j] = b2f(u[j]);
    }
  } else {  // fp32 inputs
    const float* base = (const float*)penta + (size_t)w*2560 + lane*8;
    #pragma unroll
    for (int i=0;i<5;i++){
      float4 f0 = *(const float4*)(base + i*512);
      float4 f1 = *(const float4*)(base + i*512 + 4);
      pf[i][0]=f0.x; pf[i][1]=f0.y; pf[i][2]=f0.z; pf[i][3]=f0.w;
      pf[i][4]=f1.x; pf[i][5]=f1.y; pf[i][6]=f1.z; pf[i][7]=f1.w;
    }
  }
  double acc[15];
  #pragma unroll
  for (int k=0;k<15;k++) acc[k]=0.0;
  #pragma unroll
  for (int j=0;j<8;j++){
    double p[5];
    #pragma unroll
    for (int i=0;i<5;i++) p[i] = (double)pf[i][j];
    double mean = (p[0]+p[1]+p[2]+p[3]+p[4])*0.2;
    int idx=0;
    #pragma unroll
    for (int a=0;a<5;a++)
      #pragma unroll
      for (int b=a+1;b<5;b++){ double d=p[a]-p[b]; acc[idx++] += d*d; }
    #pragma unroll
    for (int i=0;i<5;i++){ double d=p[i]-mean; acc[10+i] += d*d; }
  }
  #pragma unroll
  for (int k=0;k<15;k++){
    double s = acc[k];
    for (int off=32; off; off>>=1) s += shfl_xor_d(s, off);
    acc[k]=s;     // butterfly: every lane holds the full sum (bit-identical to old path)
  }
  if (lane != 0) return;
  // ---- coords math (identical arithmetic to old coords_kernel) ----
  double ds[10], cd2[5];
  #pragma unroll
  for (int k=0;k<10;k++) ds[k]=acc[k];
  #pragma unroll
  for (int k=0;k<5;k++) cd2[k]=acc[10+k];
  // Cayley-Menger with rows 0,1 pre-swapped; no pivoting needed (pivots 1,1,~-1024,...).
  double M[6][6];
  M[0][0]=1.0; M[0][1]=0.0; M[0][2]=ds[0]; M[0][3]=ds[1]; M[0][4]=ds[2]; M[0][5]=ds[3];
  M[1][0]=0.0; M[1][1]=1.0; M[1][2]=1.0;   M[1][3]=1.0;   M[1][4]=1.0;   M[1][5]=1.0;
  M[2][0]=1.0; M[2][1]=ds[0]; M[2][2]=0.0;   M[2][3]=ds[4]; M[2][4]=ds[5]; M[2][5]=ds[6];
  M[3][0]=1.0; M[3][1]=ds[1]; M[3][2]=ds[4]; M[3][3]=0.0;   M[3][4]=ds[7]; M[3][5]=ds[8];
  M[4][0]=1.0; M[4][1]=ds[2]; M[4][2]=ds[5]; M[4][3]=ds[7]; M[4][4]=0.0;   M[4][5]=ds[9];
  M[5][0]=1.0; M[5][1]=ds[3]; M[5][2]=ds[6]; M[5][3]=ds[8]; M[5][4]=ds[9]; M[5][5]=0.0;
  double det=1.0;
  #pragma unroll
  for (int c=0;c<6;c++){
    double pv = M[c][c];
    det *= pv;
    double inv = 1.0/pv;
    #pragma unroll
    for (int r=c+1;r<6;r++){
      double fq = M[r][c]*inv;
      #pragma unroll
      for (int cc=c+1;cc<6;cc++) M[r][cc] -= fq*M[c][cc];
    }
  }
  double volume = sqrt(fmax(det/9216.0, 0.0));
  double vn = 1.0/(1.0+exp(-10.0*volume));
  double me=0.0, e[10];
  #pragma unroll
  for (int k=0;k<10;k++){ e[k]=sqrt(ds[k]); me+=e[k]; }
  me *= 0.1;
  double var=0.0;
  #pragma unroll
  for (int k=0;k<10;k++){ double d=e[k]-me; var+=d*d; }
  double se = sqrt(var/9.0);                    // ddof=1
  double er = 1.0/(1.0+exp(-(se/(me+1e-6))));
  double mc=0.0, cd[5];
  #pragma unroll
  for (int k=0;k<5;k++){ cd[k]=sqrt(cd2[k]); mc+=cd[k]; }
  mc *= 0.2;
  double v2=0.0;
  #pragma unroll
  for (int k=0;k<5;k++){ double d=cd[k]-mc; v2+=d*d; }
  double sp = sqrt(v2/4.0);                     // ddof=1
  double sn = 1.0/(1.0+exp(-sp));
  const double EPSd = 1e-6;
  double x = 0.4*vn + 0.3*er + 0.3*sn;
  x = fmin(fmax(x, EPSd), 1.0-EPSd);
  double bump = (vn+er+sn)*0.01;
  double cv=0.0, factor=0.5;
  #pragma unroll
  for (int it=0; it<8; it++){
    double xs = x*3.0;
    double frac = xs - floor(xs);
    if (xs >= 2.0) cv += factor;
    x = fmin(fmax(frac + bump, EPSd), 1.0-EPSd);
    factor *= 0.5;
  }
  cv = fmin(fmax(cv,0.0),1.0);
  ctok[slot] = (int)(cv*256.0 + 0.5);           // exact multiple of 1/256 -> exact int (max 255)
}

// ---------------- Stage 3: top-64 neighbors + self-computed representative ----------------
__global__ __launch_bounds__(256) void routes_kernel(const int* __restrict__ ctok,
                                                     int* __restrict__ repq,
                                                     int* __restrict__ routes){
  __shared__ int cs[NSEQ];
  __shared__ int hist[256];
  __shared__ int scn[256];
  __shared__ int cnts[256];
  __shared__ int params[3];   // T, need, out-counter
  __shared__ int repsh;
  int tid = threadIdx.x;
  int q = blockIdx.x;
  for (int j=tid; j<NSEQ; j+=256) cs[j] = ctok[j];
  hist[tid] = 0;
  if (tid==0){ params[2]=0; repsh=0x7fffffff; }
  __syncthreads();
  int cq = cs[q];
  int base = tid*8;
  // representative = lowest index with equal coord (q itself matches, so repsh <= q)
  {
    int myrep = 0x7fffffff;
    #pragma unroll
    for (int i=0;i<8;i++){
      if (cs[base+i]==cq && myrep==0x7fffffff) myrep = base+i;
    }
    if (myrep != 0x7fffffff) atomicMin(&repsh, myrep);
  }
  __syncthreads();
  if (tid==0) repq[q] = repsh;
  if (repsh != q) return;      // same coord -> identical routes; computed once per group
  int dloc[8];
  #pragma unroll
  for (int i=0;i<8;i++){
    int d = cs[base+i] - cq; d = d<0 ? -d : d;
    dloc[i] = d;
    atomicAdd(&hist[d], 1);
  }
  __syncthreads();
  // parallel inclusive scan of hist -> scn
  scn[tid] = hist[tid];
  __syncthreads();
  #pragma unroll
  for (int off=1; off<256; off<<=1){
    int cur = scn[tid];
    int add = (tid>=off) ? scn[tid-off] : 0;
    __syncthreads();
    scn[tid] = cur + add;
    __syncthreads();
  }
  {
    int incl = scn[tid];
    int prev = (tid==0) ? 0 : scn[tid-1];
    if (incl >= 64 && prev < 64){ params[0]=tid; params[1]=64-prev; }
  }
  __syncthreads();
  int T=params[0], need=params[1];
  int ceq=0;
  #pragma unroll
  for (int i=0;i<8;i++) ceq += (dloc[i]==T) ? 1 : 0;
  // parallel scan of per-thread equal-counts -> exclusive rank base
  cnts[tid]=ceq;
  __syncthreads();
  #pragma unroll
  for (int off=1; off<256; off<<=1){
    int cur = cnts[tid];
    int add = (tid>=off) ? cnts[tid-off] : 0;
    __syncthreads();
    cnts[tid] = cur + add;
    __syncthreads();
  }
  int rank = cnts[tid] - ceq;
  int* rq = routes + q*64;
  #pragma unroll
  for (int i=0;i<8;i++){
    int d = dloc[i];
    bool sel = false;
    if (d < T) sel = true;
    else if (d == T){ sel = (rank < need); rank++; }
    if (sel){
      int pos = atomicAdd(&params[2], 1);
      rq[pos] = base + i;   // set semantics: order within the 64 doesn't matter for softmax
    }
  }
}

// ---------------- Stages 4/6: LDS-free direct-global bf16 MFMA GEMM ----------------
template<int C_FOLLOW>
__global__ __launch_bounds__(256) void gemm_direct(const u16* __restrict__ A,
    const u16* __restrict__ Wt, const void* __restrict__ bias, void* __restrict__ Cout,
    const u16* __restrict__ penta, int M, int N, int K)
{
  int f = detect_flag(penta);
  bool c_bf16 = C_FOLLOW ? (f==1) : true;
  int tid = threadIdx.x;
  int wv = tid>>6, lane = tid&63, lr = lane&15, lq = lane>>4;
  int m0 = blockIdx.y<<6, n0 = blockIdx.x<<6;
  const u16* Arow = A  + (size_t)(m0 + (wv<<4) + lr)*K + (lq<<3);
  const u16* Wr0  = Wt + (size_t)(n0 + lr)*K + (lq<<3);
  size_t wstep = (size_t)16*K;
  floatx4 acc[4];
  #pragma unroll
  for (int t=0;t<4;t++) acc[t] = (floatx4){0.f,0.f,0.f,0.f};
  #pragma unroll 4
  for (int k0=0;k0<K;k0+=32){
    short8 af = *(const short8*)(Arow + k0);
    #pragma unroll
    for (int t4=0;t4<4;t4++){
      short8 bfv = *(const short8*)(Wr0 + (size_t)t4*wstep + k0);
      acc[t4] = __builtin_amdgcn_mfma_f32_16x16x32_bf16(af, bfv, acc[t4], 0, 0, 0);
    }
  }
  // C/D: row = lq*4 + r, col = lane&15
  #pragma unroll
  for (int t4=0;t4<4;t4++){
    #pragma unroll
    for (int r=0;r<4;r++){
      int m = m0 + (wv<<4) + (lq<<2) + r;
      int n = n0 + (t4<<4) + lr;
      float bv = f ? b2f(((const u16*)bias)[n]) : ((const float*)bias)[n];
      float val = acc[t4][r] + bv;
      if (c_bf16) ((u16*)Cout)[(size_t)m*N + n] = f2b(val);
      else        ((float*)Cout)[(size_t)m*N + n] = val;
    }
  }
}

// ---------------- Stage 5: gather attention, 4 queries/block (1 per wave) ----------------
// All memory phases use COALESCED full-row loads (1 KB per wave instruction):
//  k-phase: for each neighbor j, lane covers q/k dims [lane*8,lane*8+8); partial dot
//           reduced over the 8-lane head group via shfl_xor(1,2,4); score -> LDS.
//  softmax: lane=(h,jg) handles 8 scores of head h; group-reduce max/sum; probs -> LDS.
//  v-phase: lane=(h,dg) accumulates 8 output dims over j with coalesced v-row loads.
__global__ __launch_bounds__(256) void attn_kernel(const u16* __restrict__ qkv,
                                                   const int* __restrict__ routes,
                                                   const int* __restrict__ repq,
                                                   u16* __restrict__ outa){
  __shared__ float sc[4][8*65];   // (65h+j)%32=(h+j)%32 -> conflict-free across heads
  __shared__ int rbuf[4][64];
  int tid = threadIdx.x;
  int wv = tid>>6, lane = tid&63;
  int bq = blockIdx.x*4 + wv;     // = b*2048 + q
  int b = bq >> 11;
  int q = bq & 2047;
  rbuf[wv][lane] = routes[(repq[q]<<6) + lane];
  int h8 = lane>>3;               // head this lane's dims belong to
  const u16* kb = qkv + (size_t)(b<<11)*1536;
  // my 8 q dims (coalesced 1KB load across the wave)
  float qv[8];
  {
    u16x8 qraw = *(const u16x8*)(kb + (size_t)q*1536 + lane*8);
    #pragma unroll
    for (int t=0;t<8;t++) qv[t] = b2f(qraw[t]);
  }
  __syncthreads();
  // k-phase
  for (int j=0;j<64;j++){
    int rj = rbuf[wv][j];
    u16x8 kraw = *(const u16x8*)(kb + (size_t)rj*1536 + 512 + lane*8);
    float p = 0.f;
    #pragma unroll
    for (int t=0;t<8;t++) p = fmaf(b2f(kraw[t]), qv[t], p);
    p += __shfl_xor(p, 1, 64);
    p += __shfl_xor(p, 2, 64);
    p += __shfl_xor(p, 4, 64);
    if ((lane&7)==0) sc[wv][h8*65 + j] = p * 0.125f;   // 1/sqrt(64)
  }
  __syncthreads();
  // softmax per head (8-lane group owns a head; each lane 8 scores)
  {
    int jg = (lane&7)<<3;
    float sv[8];
    float m = -1e30f;
    #pragma unroll
    for (int t=0;t<8;t++){ sv[t] = sc[wv][h8*65 + jg + t]; m = fmaxf(m, sv[t]); }
    m = fmaxf(m, __shfl_xor(m, 1, 64));
    m = fmaxf(m, __shfl_xor(m, 2, 64));
    m = fmaxf(m, __shfl_xor(m, 4, 64));
    float s = 0.f;
    #pragma unroll
    for (int t=0;t<8;t++){ sv[t] = expf(sv[t]-m); s += sv[t]; }
    s += __shfl_xor(s, 1, 64);
    s += __shfl_xor(s, 2, 64);
    s += __shfl_xor(s, 4, 64);
    float inv = 1.f/s;
    #pragma unroll
    for (int t=0;t<8;t++) sc[wv][h8*65 + jg + t] = sv[t]*inv;
  }
  __syncthreads();
  // v-phase: lane=(h8, dg) accumulates out dims [h8*64+dg, +8)
  int dg = (lane&7)<<3;
  const u16* vb = kb + 1024 + (h8<<6) + dg;
  float acc8[8];
  #pragma unroll
  for (int t=0;t<8;t++) acc8[t]=0.f;
  for (int j=0;j<64;j++){
    float p = sc[wv][h8*65 + j];
    u16x8 v8 = *(const u16x8*)(vb + (size_t)rbuf[wv][j]*1536);
    #pragma unroll
    for (int t=0;t<8;t++) acc8[t] = fmaf(p, b2f(v8[t]), acc8[t]);
  }
  u16x8 o;
  #pragma unroll
  for (int t=0;t<8;t++) o[t] = f2b(acc8[t]);
  *(u16x8*)(outa + (size_t)bq*512 + (h8<<6) + dg) = o;
}

extern "C" void kernel_launch(void* const* d_in, const int* in_sizes, int n_in,
                              void* d_out, int out_size, void* d_ws, size_t ws_size,
                              hipStream_t stream) {
  const void* penta = d_in[0];   // [32000,5,512]
  const void* x     = d_in[1];   // [2,2048,512]
  const int*  tok   = (const int*)d_in[2];   // [2048]
  const void* Wqkv  = d_in[3];   // [512,1536]
  const void* bqkv  = d_in[4];   // [1536]
  const void* Wout  = d_in[5];   // [512,512]
  const void* bout  = d_in[6];   // [512]

  char* ws = (char*)d_ws;
  int*    ctok   = (int*)   (ws + 0);          // 8192 B
  int*    repq   = (int*)   (ws + 8192);       // 8192 B
  int*    routes = (int*)   (ws + 16384);      // 524288 B   (end 540672)
  u16*    xb     = (u16*)   (ws + 1048576);    // 4194304 B  (end 5242880)
  u16*    Wt1    = (u16*)   (ws + 5242880);    // 1572864 B  (end 6815744)
  u16*    Wt2    = (u16*)   (ws + 6815744);    // 524288 B   (end 7340032)
  u16*    qkv    = (u16*)   (ws + 7340032);    // 12582912 B (end 19922944)
  u16*    attn   = (u16*)   (ws + 19922944);   // 4194304 B  (end 24117248 ~ 23 MB)

  prep_kernel<<<dim3(2048), dim3(256), 0, stream>>>(x, Wqkv, Wout, (const u16*)penta, xb, Wt1, Wt2);
  penta_coords_kernel<<<dim3(512), dim3(256), 0, stream>>>(penta, tok, ctok);
  routes_kernel<<<dim3(2048), dim3(256), 0, stream>>>(ctok, repq, routes);
  gemm_direct<0><<<dim3(24,64), dim3(256), 0, stream>>>(xb, Wt1, bqkv, (void*)qkv, (const u16*)penta, 4096, 1536, 512);
  attn_kernel<<<dim3(1024), dim3(256), 0, stream>>>(qkv, routes, repq, attn);
  gemm_direct<1><<<dim3(8,64), dim3(256), 0, stream>>>(attn, Wt2, bout, d_out, (const u16*)penta, 4096, 512, 512);
}

// Round 5
// 489.927 us; speedup vs baseline: 1.0740x; 1.0573x over previous
//
#include <hip/hip_runtime.h>
#include <math.h>

// Pipeline (float-input dtype auto-detected bf16 vs fp32; internal fp64/fp32/bf16), 5 launches:
//  1. prep_coords : fused 3-way grid —
//                   [0,1024)    x -> bf16 xb (SKIPPED entirely when inputs already bf16;
//                               gemm then reads x directly via the flag)
//                   [1024,2048) Wqkv/Wout -> Wt1/Wt2 (bf16, transposed)
//                   [2048,2560) one wave per TOKEN SLOT: 15 fp64 pair/centroid sums via
//                               butterfly shfl reduce, lane 0 runs fp64 Cayley-Menger det
//                               + stats + cantor -> ctok[slot]
//  2. routes      : per-query block caches ctok in LDS, computes representative (min index,
//                   equal coord) -> repq[q]; non-reps exit; reps do histogram top-64.
//  3. gemm qkv    : LDS-free direct-global bf16 MFMA; each wave owns 32m x 64n (2 m-subtiles)
//                   -> halves the duplicated B-row traffic vs 16m/wave, 2x MFMA density.
//  4. attn        : 4 queries/block (1/wave); coalesced row loads; routes shared via repq.
//  5. gemm out    : same direct GEMM -> d_out (dtype per flag)

typedef unsigned short u16;
typedef short short8 __attribute__((ext_vector_type(8)));
typedef u16 u16x8 __attribute__((ext_vector_type(8)));
typedef float floatx4 __attribute__((ext_vector_type(4)));

#define NVOCAB 32000
#define NSEQ 2048

__device__ inline float b2f(u16 u){
  union{unsigned int i; float f;} x; x.i = ((unsigned int)u)<<16; return x.f;
}
__device__ inline u16 f2b(float f){
  union{float f; unsigned int u;} x; x.f = f;
  unsigned int u = x.u;
  u += 0x7fffu + ((u >> 16) & 1u);   // RNE
  return (u16)(u >> 16);
}
__device__ inline double shfl_xor_d(double v, int m){
  union{double d; int i[2];} x; x.d = v;
  x.i[0] = __shfl_xor(x.i[0], m, 64);
  x.i[1] = __shfl_xor(x.i[1], m, 64);
  return x.d;
}
// Per-wave input dtype detection: u16 at even indices; bf16 values of N(0,1) data have
// exponent in [96,144], fp32 low-halves don't.
__device__ inline int detect_flag(const u16* __restrict__ p){
  int lane = threadIdx.x & 63;
  u16 u = p[lane*2];
  int e = (u >> 7) & 0xff;
  unsigned long long m = __ballot(e >= 96 && e <= 144);
  return (m == ~0ull) ? 1 : 0;
}

// ---------------- Stage 1: fused prep (x-conv + W transposes) + penta coords ----------------
__global__ __launch_bounds__(256) void prep_coords_kernel(const void* __restrict__ x,
                                                          const void* __restrict__ W1,
                                                          const void* __restrict__ W2,
                                                          const void* __restrict__ penta,
                                                          const int* __restrict__ tok,
                                                          u16* __restrict__ xb,
                                                          u16* __restrict__ Wt1,
                                                          u16* __restrict__ Wt2,
                                                          int* __restrict__ ctok){
  __shared__ u16 tile[32][33];
  int f = detect_flag((const u16*)penta);
  int bid = blockIdx.x;
  if (bid < 1024){
    if (f) return;                 // x already bf16: gemm reads it directly, no copy needed
    size_t i = ((size_t)bid*256 + threadIdx.x)*8;
    const float* xf = (const float*)x + i;
    float4 a = *(const float4*)xf;
    float4 b = *(const float4*)(xf+4);
    u16x8 o;
    o[0]=f2b(a.x); o[1]=f2b(a.y); o[2]=f2b(a.z); o[3]=f2b(a.w);
    o[4]=f2b(b.x); o[5]=f2b(b.y); o[6]=f2b(b.z); o[7]=f2b(b.w);
    *(u16x8*)(xb+i) = o;
    return;
  }
  if (bid < 2048){
    // W[K][N] -> Wt[N][K] bf16, K=512
    int idx = bid - 1024;          // 0..1023
    int bx = idx & 63;             // 0..63
    int k0 = (idx >> 6) * 32;      // 0..480
    const int K = 512;
    const void* W; u16* Wt; int N, n0;
    if (bx < 48){ W = W1; Wt = Wt1; N = 1536; n0 = bx*32; }
    else        { W = W2; Wt = Wt2; N = 512;  n0 = (bx-48)*32; }
    int tx = threadIdx.x & 31, ty = threadIdx.x >> 5;
    #pragma unroll
    for (int i=0;i<32;i+=8){
      int k = k0+ty+i, n = n0+tx;
      u16 v = f ? ((const u16*)W)[(size_t)k*N + n]
                : f2b(((const float*)W)[(size_t)k*N + n]);
      tile[ty+i][tx] = v;
    }
    __syncthreads();
    #pragma unroll
    for (int i=0;i<32;i+=8){
      Wt[(size_t)(n0+ty+i)*K + k0+tx] = tile[tx][ty+i];
    }
    return;
  }
  // ---- penta sums + coords: one wave per token slot ----
  int slot = (bid-2048)*4 + (threadIdx.x>>6);   // 0..2047
  int w = tok[slot];
  int lane = threadIdx.x & 63;
  float pf[5][8];
  if (f){   // bf16 inputs
    const u16* base = (const u16*)penta + (size_t)w*2560 + lane*8;
    #pragma unroll
    for (int i=0;i<5;i++){
      u16x8 u = *(const u16x8*)(base + i*512);
      #pragma unroll
      for (int j=0;j<8;j++) pf[i][j] = b2f(u[j]);
    }
  } else {  // fp32 inputs
    const float* base = (const float*)penta + (size_t)w*2560 + lane*8;
    #pragma unroll
    for (int i=0;i<5;i++){
      float4 f0 = *(const float4*)(base + i*512);
      float4 f1 = *(const float4*)(base + i*512 + 4);
      pf[i][0]=f0.x; pf[i][1]=f0.y; pf[i][2]=f0.z; pf[i][3]=f0.w;
      pf[i][4]=f1.x; pf[i][5]=f1.y; pf[i][6]=f1.z; pf[i][7]=f1.w;
    }
  }
  double acc[15];
  #pragma unroll
  for (int k=0;k<15;k++) acc[k]=0.0;
  #pragma unroll
  for (int j=0;j<8;j++){
    double p[5];
    #pragma unroll
    for (int i=0;i<5;i++) p[i] = (double)pf[i][j];
    double mean = (p[0]+p[1]+p[2]+p[3]+p[4])*0.2;
    int idx=0;
    #pragma unroll
    for (int a=0;a<5;a++)
      #pragma unroll
      for (int b=a+1;b<5;b++){ double d=p[a]-p[b]; acc[idx++] += d*d; }
    #pragma unroll
    for (int i=0;i<5;i++){ double d=p[i]-mean; acc[10+i] += d*d; }
  }
  #pragma unroll
  for (int k=0;k<15;k++){
    double s = acc[k];
    for (int off=32; off; off>>=1) s += shfl_xor_d(s, off);
    acc[k]=s;     // butterfly: every lane holds the full sum (bit-identical to old path)
  }
  if (lane != 0) return;
  double ds[10], cd2[5];
  #pragma unroll
  for (int k=0;k<10;k++) ds[k]=acc[k];
  #pragma unroll
  for (int k=0;k<5;k++) cd2[k]=acc[10+k];
  // Cayley-Menger with rows 0,1 pre-swapped; no pivoting needed (pivots 1,1,~-1024,...).
  double M[6][6];
  M[0][0]=1.0; M[0][1]=0.0; M[0][2]=ds[0]; M[0][3]=ds[1]; M[0][4]=ds[2]; M[0][5]=ds[3];
  M[1][0]=0.0; M[1][1]=1.0; M[1][2]=1.0;   M[1][3]=1.0;   M[1][4]=1.0;   M[1][5]=1.0;
  M[2][0]=1.0; M[2][1]=ds[0]; M[2][2]=0.0;   M[2][3]=ds[4]; M[2][4]=ds[5]; M[2][5]=ds[6];
  M[3][0]=1.0; M[3][1]=ds[1]; M[3][2]=ds[4]; M[3][3]=0.0;   M[3][4]=ds[7]; M[3][5]=ds[8];
  M[4][0]=1.0; M[4][1]=ds[2]; M[4][2]=ds[5]; M[4][3]=ds[7]; M[4][4]=0.0;   M[4][5]=ds[9];
  M[5][0]=1.0; M[5][1]=ds[3]; M[5][2]=ds[6]; M[5][3]=ds[8]; M[5][4]=ds[9]; M[5][5]=0.0;
  double det=1.0;
  #pragma unroll
  for (int c=0;c<6;c++){
    double pv = M[c][c];
    det *= pv;
    double inv = 1.0/pv;
    #pragma unroll
    for (int r=c+1;r<6;r++){
      double fq = M[r][c]*inv;
      #pragma unroll
      for (int cc=c+1;cc<6;cc++) M[r][cc] -= fq*M[c][cc];
    }
  }
  double volume = sqrt(fmax(det/9216.0, 0.0));
  double vn = 1.0/(1.0+exp(-10.0*volume));
  double me=0.0, e[10];
  #pragma unroll
  for (int k=0;k<10;k++){ e[k]=sqrt(ds[k]); me+=e[k]; }
  me *= 0.1;
  double var=0.0;
  #pragma unroll
  for (int k=0;k<10;k++){ double d=e[k]-me; var+=d*d; }
  double se = sqrt(var/9.0);                    // ddof=1
  double er = 1.0/(1.0+exp(-(se/(me+1e-6))));
  double mc=0.0, cd[5];
  #pragma unroll
  for (int k=0;k<5;k++){ cd[k]=sqrt(cd2[k]); mc+=cd[k]; }
  mc *= 0.2;
  double v2=0.0;
  #pragma unroll
  for (int k=0;k<5;k++){ double d=cd[k]-mc; v2+=d*d; }
  double sp = sqrt(v2/4.0);                     // ddof=1
  double sn = 1.0/(1.0+exp(-sp));
  const double EPSd = 1e-6;
  double xx = 0.4*vn + 0.3*er + 0.3*sn;
  xx = fmin(fmax(xx, EPSd), 1.0-EPSd);
  double bump = (vn+er+sn)*0.01;
  double cv=0.0, factor=0.5;
  #pragma unroll
  for (int it=0; it<8; it++){
    double xs = xx*3.0;
    double frac = xs - floor(xs);
    if (xs >= 2.0) cv += factor;
    xx = fmin(fmax(frac + bump, EPSd), 1.0-EPSd);
    factor *= 0.5;
  }
  cv = fmin(fmax(cv,0.0),1.0);
  ctok[slot] = (int)(cv*256.0 + 0.5);           // exact multiple of 1/256 -> exact int (max 255)
}

// ---------------- Stage 2: top-64 neighbors + self-computed representative ----------------
__global__ __launch_bounds__(256) void routes_kernel(const int* __restrict__ ctok,
                                                     int* __restrict__ repq,
                                                     int* __restrict__ routes){
  __shared__ int cs[NSEQ];
  __shared__ int hist[256];
  __shared__ int scn[256];
  __shared__ int cnts[256];
  __shared__ int params[3];   // T, need, out-counter
  __shared__ int repsh;
  int tid = threadIdx.x;
  int q = blockIdx.x;
  for (int j=tid; j<NSEQ; j+=256) cs[j] = ctok[j];
  hist[tid] = 0;
  if (tid==0){ params[2]=0; repsh=0x7fffffff; }
  __syncthreads();
  int cq = cs[q];
  int base = tid*8;
  // representative = lowest index with equal coord (q itself matches, so repsh <= q)
  {
    int myrep = 0x7fffffff;
    #pragma unroll
    for (int i=0;i<8;i++){
      if (cs[base+i]==cq && myrep==0x7fffffff) myrep = base+i;
    }
    if (myrep != 0x7fffffff) atomicMin(&repsh, myrep);
  }
  __syncthreads();
  if (tid==0) repq[q] = repsh;
  if (repsh != q) return;      // same coord -> identical routes; computed once per group
  int dloc[8];
  #pragma unroll
  for (int i=0;i<8;i++){
    int d = cs[base+i] - cq; d = d<0 ? -d : d;
    dloc[i] = d;
    atomicAdd(&hist[d], 1);
  }
  __syncthreads();
  // parallel inclusive scan of hist -> scn
  scn[tid] = hist[tid];
  __syncthreads();
  #pragma unroll
  for (int off=1; off<256; off<<=1){
    int cur = scn[tid];
    int add = (tid>=off) ? scn[tid-off] : 0;
    __syncthreads();
    scn[tid] = cur + add;
    __syncthreads();
  }
  {
    int incl = scn[tid];
    int prev = (tid==0) ? 0 : scn[tid-1];
    if (incl >= 64 && prev < 64){ params[0]=tid; params[1]=64-prev; }
  }
  __syncthreads();
  int T=params[0], need=params[1];
  int ceq=0;
  #pragma unroll
  for (int i=0;i<8;i++) ceq += (dloc[i]==T) ? 1 : 0;
  // parallel scan of per-thread equal-counts -> exclusive rank base
  cnts[tid]=ceq;
  __syncthreads();
  #pragma unroll
  for (int off=1; off<256; off<<=1){
    int cur = cnts[tid];
    int add = (tid>=off) ? cnts[tid-off] : 0;
    __syncthreads();
    cnts[tid] = cur + add;
    __syncthreads();
  }
  int rank = cnts[tid] - ceq;
  int* rq = routes + q*64;
  #pragma unroll
  for (int i=0;i<8;i++){
    int d = dloc[i];
    bool sel = false;
    if (d < T) sel = true;
    else if (d == T){ sel = (rank < need); rank++; }
    if (sel){
      int pos = atomicAdd(&params[2], 1);
      rq[pos] = base + i;   // set semantics: order within the 64 doesn't matter for softmax
    }
  }
}

// ---------------- Stages 3/5: LDS-free direct-global bf16 MFMA GEMM, 32m/wave ----------------
// Block = 128m x 64n (4 waves stacked in m, each wave 32m x 64n = 2 m-subtiles x 4 n-subtiles).
// vs 16m/wave this halves the per-block-duplicated B-row traffic and doubles MFMA density.
// A pointer selected by flag: Af1 when inputs are bf16 (raw x), Af0 otherwise (converted xb).
template<int C_FOLLOW>
__global__ __launch_bounds__(256) void gemm_direct(const u16* __restrict__ Af1,
    const u16* __restrict__ Af0, const u16* __restrict__ Wt,
    const void* __restrict__ bias, void* __restrict__ Cout,
    const u16* __restrict__ penta, int M, int N, int K)
{
  int f = detect_flag(penta);
  const u16* A = f ? Af1 : Af0;
  bool c_bf16 = C_FOLLOW ? (f==1) : true;
  int tid = threadIdx.x;
  int wv = tid>>6, lane = tid&63, lr = lane&15, lq = lane>>4;
  int m0 = blockIdx.y<<7, n0 = blockIdx.x<<6;
  const u16* Arow0 = A  + (size_t)(m0 + (wv<<5) + lr)*K + (lq<<3);
  const u16* Arow1 = Arow0 + (size_t)16*K;
  const u16* Wr0   = Wt + (size_t)(n0 + lr)*K + (lq<<3);
  size_t wstep = (size_t)16*K;
  floatx4 acc[2][4];
  #pragma unroll
  for (int mt=0;mt<2;mt++)
    #pragma unroll
    for (int t=0;t<4;t++) acc[mt][t] = (floatx4){0.f,0.f,0.f,0.f};
  #pragma unroll 4
  for (int k0=0;k0<K;k0+=32){
    short8 af0 = *(const short8*)(Arow0 + k0);
    short8 af1 = *(const short8*)(Arow1 + k0);
    #pragma unroll
    for (int t4=0;t4<4;t4++){
      short8 bfv = *(const short8*)(Wr0 + (size_t)t4*wstep + k0);
      acc[0][t4] = __builtin_amdgcn_mfma_f32_16x16x32_bf16(af0, bfv, acc[0][t4], 0, 0, 0);
      acc[1][t4] = __builtin_amdgcn_mfma_f32_16x16x32_bf16(af1, bfv, acc[1][t4], 0, 0, 0);
    }
  }
  // C/D: row = lq*4 + r, col = lane&15
  #pragma unroll
  for (int mt=0;mt<2;mt++){
    #pragma unroll
    for (int t4=0;t4<4;t4++){
      #pragma unroll
      for (int r=0;r<4;r++){
        int m = m0 + (wv<<5) + (mt<<4) + (lq<<2) + r;
        int n = n0 + (t4<<4) + lr;
        float bv = f ? b2f(((const u16*)bias)[n]) : ((const float*)bias)[n];
        float val = acc[mt][t4][r] + bv;
        if (c_bf16) ((u16*)Cout)[(size_t)m*N + n] = f2b(val);
        else        ((float*)Cout)[(size_t)m*N + n] = val;
      }
    }
  }
}

// ---------------- Stage 4: gather attention, 4 queries/block (1 per wave) ----------------
// All memory phases use COALESCED full-row loads (1 KB per wave instruction):
//  k-phase: for each neighbor j, lane covers q/k dims [lane*8,lane*8+8); partial dot
//           reduced over the 8-lane head group via shfl_xor(1,2,4); score -> LDS.
//  softmax: lane=(h,jg) handles 8 scores of head h; group-reduce max/sum; probs -> LDS.
//  v-phase: lane=(h,dg) accumulates 8 output dims over j with coalesced v-row loads.
__global__ __launch_bounds__(256) void attn_kernel(const u16* __restrict__ qkv,
                                                   const int* __restrict__ routes,
                                                   const int* __restrict__ repq,
                                                   u16* __restrict__ outa){
  __shared__ float sc[4][8*65];   // (65h+j)%32=(h+j)%32 -> conflict-free across heads
  __shared__ int rbuf[4][64];
  int tid = threadIdx.x;
  int wv = tid>>6, lane = tid&63;
  int bq = blockIdx.x*4 + wv;     // = b*2048 + q
  int b = bq >> 11;
  int q = bq & 2047;
  rbuf[wv][lane] = routes[(repq[q]<<6) + lane];
  int h8 = lane>>3;               // head this lane's dims belong to
  const u16* kb = qkv + (size_t)(b<<11)*1536;
  // my 8 q dims (coalesced 1KB load across the wave)
  float qv[8];
  {
    u16x8 qraw = *(const u16x8*)(kb + (size_t)q*1536 + lane*8);
    #pragma unroll
    for (int t=0;t<8;t++) qv[t] = b2f(qraw[t]);
  }
  __syncthreads();
  // k-phase
  for (int j=0;j<64;j++){
    int rj = rbuf[wv][j];
    u16x8 kraw = *(const u16x8*)(kb + (size_t)rj*1536 + 512 + lane*8);
    float p = 0.f;
    #pragma unroll
    for (int t=0;t<8;t++) p = fmaf(b2f(kraw[t]), qv[t], p);
    p += __shfl_xor(p, 1, 64);
    p += __shfl_xor(p, 2, 64);
    p += __shfl_xor(p, 4, 64);
    if ((lane&7)==0) sc[wv][h8*65 + j] = p * 0.125f;   // 1/sqrt(64)
  }
  __syncthreads();
  // softmax per head (8-lane group owns a head; each lane 8 scores)
  {
    int jg = (lane&7)<<3;
    float sv[8];
    float m = -1e30f;
    #pragma unroll
    for (int t=0;t<8;t++){ sv[t] = sc[wv][h8*65 + jg + t]; m = fmaxf(m, sv[t]); }
    m = fmaxf(m, __shfl_xor(m, 1, 64));
    m = fmaxf(m, __shfl_xor(m, 2, 64));
    m = fmaxf(m, __shfl_xor(m, 4, 64));
    float s = 0.f;
    #pragma unroll
    for (int t=0;t<8;t++){ sv[t] = expf(sv[t]-m); s += sv[t]; }
    s += __shfl_xor(s, 1, 64);
    s += __shfl_xor(s, 2, 64);
    s += __shfl_xor(s, 4, 64);
    float inv = 1.f/s;
    #pragma unroll
    for (int t=0;t<8;t++) sc[wv][h8*65 + jg + t] = sv[t]*inv;
  }
  __syncthreads();
  // v-phase: lane=(h8, dg) accumulates out dims [h8*64+dg, +8)
  int dg = (lane&7)<<3;
  const u16* vb = kb + 1024 + (h8<<6) + dg;
  float acc8[8];
  #pragma unroll
  for (int t=0;t<8;t++) acc8[t]=0.f;
  for (int j=0;j<64;j++){
    float p = sc[wv][h8*65 + j];
    u16x8 v8 = *(const u16x8*)(vb + (size_t)rbuf[wv][j]*1536);
    #pragma unroll
    for (int t=0;t<8;t++) acc8[t] = fmaf(p, b2f(v8[t]), acc8[t]);
  }
  u16x8 o;
  #pragma unroll
  for (int t=0;t<8;t++) o[t] = f2b(acc8[t]);
  *(u16x8*)(outa + (size_t)bq*512 + (h8<<6) + dg) = o;
}

extern "C" void kernel_launch(void* const* d_in, const int* in_sizes, int n_in,
                              void* d_out, int out_size, void* d_ws, size_t ws_size,
                              hipStream_t stream) {
  const void* penta = d_in[0];   // [32000,5,512]
  const void* x     = d_in[1];   // [2,2048,512]
  const int*  tok   = (const int*)d_in[2];   // [2048]
  const void* Wqkv  = d_in[3];   // [512,1536]
  const void* bqkv  = d_in[4];   // [1536]
  const void* Wout  = d_in[5];   // [512,512]
  const void* bout  = d_in[6];   // [512]

  char* ws = (char*)d_ws;
  int*    ctok   = (int*)   (ws + 0);          // 8192 B
  int*    repq   = (int*)   (ws + 8192);       // 8192 B
  int*    routes = (int*)   (ws + 16384);      // 524288 B   (end 540672)
  u16*    xb     = (u16*)   (ws + 1048576);    // 4194304 B  (end 5242880)
  u16*    Wt1    = (u16*)   (ws + 5242880);    // 1572864 B  (end 6815744)
  u16*    Wt2    = (u16*)   (ws + 6815744);    // 524288 B   (end 7340032)
  u16*    qkv    = (u16*)   (ws + 7340032);    // 12582912 B (end 19922944)
  u16*    attn   = (u16*)   (ws + 19922944);   // 4194304 B  (end 24117248 ~ 23 MB)

  prep_coords_kernel<<<dim3(2560), dim3(256), 0, stream>>>(x, Wqkv, Wout, penta, tok, xb, Wt1, Wt2, ctok);
  routes_kernel<<<dim3(2048), dim3(256), 0, stream>>>(ctok, repq, routes);
  gemm_direct<0><<<dim3(24,32), dim3(256), 0, stream>>>((const u16*)x, xb, Wt1, bqkv, (void*)qkv, (const u16*)penta, 4096, 1536, 512);
  attn_kernel<<<dim3(1024), dim3(256), 0, stream>>>(qkv, routes, repq, attn);
  gemm_direct<1><<<dim3(8,32), dim3(256), 0, stream>>>(attn, attn, Wt2, bout, d_out, (const u16*)penta, 4096, 512, 512);
}